// Round 7
// baseline (844.046 us; speedup 1.0000x reference)
//
#include <hip/hip_runtime.h>
#include <hip/hip_bf16.h>
#include <math.h>

// GCN stack: 3x [GCNConv + ReLU] + MLP head (64->32 relu ->40) + log_softmax.
// R6b: L2-chunked gather (R6 compile fix: nontemporal store needs a clang
// ext_vector_type, not HIP float4). hprime stored chunk-major as 4 arrays of
// 16 feats (3.2 MB each < 4 MiB per-XCD L2). Gather runs 4 passes/layer,
// each pass touches one chunk only -> random row reads become L2 hits
// instead of L3 line fetches (R4/R5: gather is random-line-throughput bound).
// out[d] = relu(dinv[d] * (h'[d] + sum_{s in N_in(d)} h'[s]) + b),
// h' = dinv * (x @ W), h' stored bf16.

#define DIMF 64

typedef float vfloat4 __attribute__((ext_vector_type(4)));

// ---------------- CSR build ----------------

__global__ __launch_bounds__(256) void zero_counts(int* cnt, int n) {
    int i = blockIdx.x * 256 + threadIdx.x;
    if (i < n) cnt[i] = 0;
}

__global__ __launch_bounds__(256) void hist_dst(const int* __restrict__ dst,
                                                int* __restrict__ cnt, int E) {
    int e = blockIdx.x * 256 + threadIdx.x;
    if (e < E) atomicAdd(&cnt[dst[e]], 1);
}

// Per-block exclusive scan of cnt -> row_start (partial), block totals -> bsum.
__global__ __launch_bounds__(256) void scan_block(const int* __restrict__ cnt,
                                                  int* __restrict__ row_start,
                                                  int* __restrict__ bsum, int n) {
    __shared__ int s[256];
    int t = threadIdx.x;
    int i = blockIdx.x * 256 + t;
    int c = (i < n) ? cnt[i] : 0;
    s[t] = c;
    __syncthreads();
    for (int off = 1; off < 256; off <<= 1) {
        int v = (t >= off) ? s[t - off] : 0;
        __syncthreads();
        s[t] += v;
        __syncthreads();
    }
    int incl = s[t];
    if (i < n) row_start[i] = incl - c;
    if (t == 255) bsum[blockIdx.x] = incl;
}

// Single-block exclusive scan of block sums (nb <= 512).
__global__ __launch_bounds__(512) void scan_bsum(int* __restrict__ bsum, int nb) {
    __shared__ int s[512];
    int t = threadIdx.x;
    int c = (t < nb) ? bsum[t] : 0;
    s[t] = c;
    __syncthreads();
    for (int off = 1; off < 512; off <<= 1) {
        int v = (t >= off) ? s[t - off] : 0;
        __syncthreads();
        s[t] += v;
        __syncthreads();
    }
    if (t < nb) bsum[t] = s[t] - c;   // exclusive
}

// row_start += bsum[blk]; cursor (=cnt reused) = row_start; dinv = rsqrt(deg+1).
__global__ __launch_bounds__(256) void scan_finalize(
    int* __restrict__ cnt, int* __restrict__ row_start,
    const int* __restrict__ bsum, float* __restrict__ dinv, int n, int E) {
    int i = blockIdx.x * 256 + threadIdx.x;
    if (i < n) {
        int c = cnt[i];
        int rsf = row_start[i] + bsum[i >> 8];
        row_start[i] = rsf;
        cnt[i] = rsf;                        // becomes the placement cursor
        dinv[i] = rsqrtf((float)c + 1.0f);   // +1 self loop
    }
    if (i == 0) row_start[n] = E;
}

__global__ __launch_bounds__(256) void place_edges(
    const int* __restrict__ src, const int* __restrict__ dst,
    int* __restrict__ cursor, int* __restrict__ csr_src, int E) {
    int e = blockIdx.x * 256 + threadIdx.x;
    if (e < E) {
        int p = atomicAdd(&cursor[dst[e]], 1);
        csr_src[p] = src[e];
    }
}

// ---------------- per-layer kernels ----------------

// hp(bf16, chunk-major) = dinv[row] * (xin @ W).
// hp layout: 4 chunks of [n][16] bf16; element (row, col) ->
// hp[(col>>4)*n*16 + row*16 + (col&15)].
__global__ __launch_bounds__(256) void gemm_scale(
    const float* __restrict__ xin, const float* __restrict__ W,
    const float* __restrict__ dinv, __hip_bfloat16* __restrict__ hp, int n)
{
    __shared__ float Ws[64 * 64];        // 16 KB
    __shared__ float Xs[32][65];         // 8.3 KB, +1 pad
    int t = threadIdx.x;
    for (int i = t; i < 64 * 64; i += 256) Ws[i] = W[i];
    int row0 = blockIdx.x * 32;
    for (int i = t; i < 32 * 64; i += 256) {
        int r = i >> 6, c = i & 63;
        int gr = row0 + r;
        Xs[r][c] = (gr < n) ? xin[(size_t)gr * DIMF + c] : 0.0f;
    }
    __syncthreads();
    int col = t & 63;
    int rbase = (t >> 6) * 8;            // 0,8,16,24
    float av[8];
#pragma unroll
    for (int rr = 0; rr < 8; rr++) av[rr] = 0.0f;
    for (int k = 0; k < 64; k++) {
        float w = Ws[k * 64 + col];      // lanes -> consecutive banks
#pragma unroll
        for (int rr = 0; rr < 8; rr++)   // Xs read is wave-broadcast
            av[rr] = fmaf(Xs[rbase + rr][k], w, av[rr]);
    }
    size_t coff = (size_t)(col >> 4) * n * 16 + (col & 15);
#pragma unroll
    for (int rr = 0; rr < 8; rr++) {
        int gr = row0 + rbase + rr;
        if (gr < n)
            hp[coff + (size_t)gr * 16] = __float2bfloat16(av[rr] * dinv[gr]);
    }
}

// One gather pass over one 16-feature chunk (3.2 MB, L2-resident per XCD).
// Wave: 8 nodes x (2 edge-slots x 4 quad-lanes). Each lane accumulates 4
// features via uint2 bf16 loads; shfl_xor(4) folds the two edge slots.
__global__ __launch_bounds__(256) void gather_chunk(
    const unsigned int* __restrict__ hpc,   // chunk base, 8 uints per node
    const int* __restrict__ row_start, const int* __restrict__ csr_src,
    const float* __restrict__ dinv, const float* __restrict__ b,
    float* __restrict__ xout, int fbase, int n)
{
    int wave = threadIdx.x >> 6;
    int lane = threadIdx.x & 63;
    int slot = lane >> 3;            // node slot 0..7
    int w    = lane & 7;
    int e2   = w >> 2;               // edge parity 0/1
    int q    = w & 3;                // quad 0..3 (features fbase+4q..+3)
    int node = (blockIdx.x * 4 + wave) * 8 + slot;
    if (node >= n) return;

    int rs = row_start[node];
    int re = row_start[node + 1];
    int deg = re - rs;

    float a0 = 0.0f, a1 = 0.0f, a2 = 0.0f, a3 = 0.0f;

#define ADD2(v)                                                            \
    {                                                                      \
        a0 += __uint_as_float((v).x << 16);                                \
        a1 += __uint_as_float((v).x & 0xffff0000u);                        \
        a2 += __uint_as_float((v).y << 16);                                \
        a3 += __uint_as_float((v).y & 0xffff0000u);                        \
    }

    if (e2 == 0) {                   // self loop, counted once
        uint2 v = *(const uint2*)(hpc + (size_t)node * 8 + q * 2);
        ADD2(v);
    }
    if (deg > e2) {
        int idx = __builtin_nontemporal_load(csr_src + rs + e2);
        for (int k = e2; k < deg; k += 2) {
            int nxt = (k + 2 < deg)
                        ? __builtin_nontemporal_load(csr_src + rs + k + 2) : 0;
            uint2 v = *(const uint2*)(hpc + (size_t)idx * 8 + q * 2);
            ADD2(v);
            idx = nxt;
        }
    }
#undef ADD2

    // fold the 2 edge slots (partner lane = lane ^ 4)
    a0 += __shfl_xor(a0, 4);
    a1 += __shfl_xor(a1, 4);
    a2 += __shfl_xor(a2, 4);
    a3 += __shfl_xor(a3, 4);

    if (e2 == 0) {
        int f = fbase + (q << 2);
        float dv = dinv[node];
        vfloat4 o;
        o.x = fmaxf(fmaf(dv, a0, b[f + 0]), 0.0f);
        o.y = fmaxf(fmaf(dv, a1, b[f + 1]), 0.0f);
        o.z = fmaxf(fmaf(dv, a2, b[f + 2]), 0.0f);
        o.w = fmaxf(fmaf(dv, a3, b[f + 3]), 0.0f);
        __builtin_nontemporal_store(o, (vfloat4*)(xout + (size_t)node * DIMF + f));
    }
}

// MLP head + log_softmax. 128 threads = 128 nodes per block.
__global__ __launch_bounds__(128) void head_kernel(
    const float* __restrict__ x, const float* __restrict__ Wp1,
    const float* __restrict__ bp1, const float* __restrict__ Wp2,
    const float* __restrict__ bp2, float* __restrict__ out, int n)
{
    __shared__ float Xs[128][65];        // 33.3 KB
    __shared__ float W1s[64 * 32];       // 8 KB
    __shared__ float W2s[32 * 40];       // 5 KB
    __shared__ float b1s[32], b2s[40];
    int t = threadIdx.x;
    for (int i = t; i < 64 * 32; i += 128) W1s[i] = Wp1[i];
    for (int i = t; i < 32 * 40; i += 128) W2s[i] = Wp2[i];
    if (t < 32) b1s[t] = bp1[t];
    if (t < 40) b2s[t] = bp2[t];
    int row0 = blockIdx.x * 128;
    for (int i = t; i < 128 * 64; i += 128) {
        int r = i >> 6, c = i & 63;
        int gr = row0 + r;
        Xs[r][c] = (gr < n) ? x[(size_t)gr * DIMF + c] : 0.0f;
    }
    __syncthreads();
    int node = row0 + t;
    if (node >= n) return;

    float h[32];
#pragma unroll
    for (int j = 0; j < 32; j++) h[j] = b1s[j];
    for (int k = 0; k < 64; k++) {
        float xv = Xs[t][k];
#pragma unroll
        for (int j = 0; j < 32; j++) h[j] = fmaf(xv, W1s[k * 32 + j], h[j]);
    }
#pragma unroll
    for (int j = 0; j < 32; j++) h[j] = h[j] > 0.0f ? h[j] : 0.0f;

    float o[40];
#pragma unroll
    for (int j = 0; j < 40; j++) o[j] = b2s[j];
    for (int k = 0; k < 32; k++) {
        float hv = h[k];
#pragma unroll
        for (int j = 0; j < 40; j++) o[j] = fmaf(hv, W2s[k * 40 + j], o[j]);
    }
    float m = o[0];
#pragma unroll
    for (int j = 1; j < 40; j++) m = fmaxf(m, o[j]);
    float sum = 0.0f;
#pragma unroll
    for (int j = 0; j < 40; j++) sum += expf(o[j] - m);
    float lse = logf(sum) + m;
    float* op = out + (size_t)node * 40;
#pragma unroll
    for (int j = 0; j < 40; j++) op[j] = o[j] - lse;
}

extern "C" void kernel_launch(void* const* d_in, const int* in_sizes, int n_in,
                              void* d_out, int out_size, void* d_ws, size_t ws_size,
                              hipStream_t stream)
{
    const float* x  = (const float*)d_in[0];
    const int*   ei = (const int*)d_in[1];
    const int E = in_sizes[1] / 2;
    const int n = in_sizes[0] / DIMF;
    const int* src = ei;
    const int* dst = ei + E;
    const float* W[3] = {(const float*)d_in[3], (const float*)d_in[5], (const float*)d_in[7]};
    const float* b[3] = {(const float*)d_in[4], (const float*)d_in[6], (const float*)d_in[8]};
    const float* Wp1 = (const float*)d_in[9];
    const float* bp1 = (const float*)d_in[10];
    const float* Wp2 = (const float*)d_in[11];
    const float* bp2 = (const float*)d_in[12];
    float* out = (float*)d_out;

    const int nb = (n + 255) / 256;      // <= 512 for n <= 131072

    // Workspace: cnt[n] | row_start[n+1] | bsum[512] | csr_src[E] |
    //            dinv[n] | hp[4 chunks x n x 16 bf16] | xbuf[n*64 f32]
    char* p = (char*)d_ws;
    int* cnt       = (int*)p;                 p += (size_t)n * 4;
    int* row_start = (int*)p;                 p += (size_t)(n + 1) * 4;
    p = (char*)(((size_t)p + 15) & ~(size_t)15);
    int* bsum      = (int*)p;                 p += 512 * 4;
    int* csr_src   = (int*)p;                 p += (size_t)E * 4;
    p = (char*)(((size_t)p + 15) & ~(size_t)15);
    float* dinv    = (float*)p;               p += (size_t)n * 4;
    p = (char*)(((size_t)p + 15) & ~(size_t)15);
    __hip_bfloat16* hp = (__hip_bfloat16*)p;  p += (size_t)n * DIMF * 2;
    p = (char*)(((size_t)p + 15) & ~(size_t)15);
    float* xbuf    = (float*)p;

    // --- CSR build (index-space atomics only) ---
    hipLaunchKernelGGL(zero_counts,  dim3(nb), dim3(256), 0, stream, cnt, n);
    hipLaunchKernelGGL(hist_dst,     dim3((E + 255) / 256), dim3(256), 0, stream, dst, cnt, E);
    hipLaunchKernelGGL(scan_block,   dim3(nb), dim3(256), 0, stream, cnt, row_start, bsum, n);
    hipLaunchKernelGGL(scan_bsum,    dim3(1), dim3(512), 0, stream, bsum, nb);
    hipLaunchKernelGGL(scan_finalize,dim3(nb), dim3(256), 0, stream, cnt, row_start, bsum, dinv, n, E);
    hipLaunchKernelGGL(place_edges,  dim3((E + 255) / 256), dim3(256), 0, stream,
                       src, dst, cnt, csr_src, E);

    // --- 3 GCN layers ---
    const float* xin = x;
    for (int l = 0; l < 3; l++) {
        hipLaunchKernelGGL(gemm_scale, dim3((n + 31) / 32), dim3(256), 0, stream,
                           xin, W[l], dinv, hp, n);
        for (int c = 0; c < 4; c++) {
            const unsigned int* hpc =
                (const unsigned int*)(hp + (size_t)c * n * 16);
            hipLaunchKernelGGL(gather_chunk, dim3((n + 31) / 32), dim3(256), 0,
                               stream, hpc, row_start, csr_src, dinv, b[l],
                               xbuf, c * 16, n);
        }
        xin = xbuf;
    }

    // --- head ---
    hipLaunchKernelGGL(head_kernel, dim3((n + 127) / 128), dim3(128), 0, stream,
                       xbuf, Wp1, bp1, Wp2, bp2, out, n);
}

// Round 8
// 539.024 us; speedup vs baseline: 1.5659x; 1.5659x over previous
//
#include <hip/hip_runtime.h>
#include <hip/hip_bf16.h>
#include <math.h>

// GCN stack: 3x [GCNConv + ReLU] + MLP head (64->32 relu ->40) + log_softmax.
// R8: gather reverted to R5 (best). CSR build replaced by two-level bucket
// sort (bucket = dst>>9, 512 nodes): LDS histograms + block-private
// contiguous writes kill the 16x dirty-line write amplification that made
// place_edges 130us (WRITE_SIZE 105MB for a 6.4MB array) and the ~60-100us
// hist_dst random atomics. Global atomics: 3.2M -> ~40K.
// out[d] = relu(dinv[d] * (h'[d] + sum_{s in N_in(d)} h'[s]) + b),
// h' = dinv * (x @ W), h' stored bf16 flat [n][64].

#define DIMF 64
#define NBA  200     // blocks for bucket count/scatter
#define BSH  9       // 512 nodes per bucket

// ---------------- CSR build (bucketed) ----------------

// A: per-block LDS histogram of dst buckets -> partial[block][256]
__global__ __launch_bounds__(256) void bucket_count(
    const int* __restrict__ dst, int* __restrict__ partial, int E, int tile)
{
    __shared__ int h[256];
    int t = threadIdx.x;
    h[t] = 0;
    __syncthreads();
    int estart = blockIdx.x * tile;
    int eend = min(E, estart + tile);
    for (int e = estart + t; e < eend; e += 256)
        atomicAdd(&h[dst[e] >> BSH], 1);
    __syncthreads();
    partial[blockIdx.x * 256 + t] = h[t];
}

// B: single block — sum partials, exclusive scan, init bucket_off & gcursor.
__global__ __launch_bounds__(256) void bucket_scan(
    const int* __restrict__ partial, int* __restrict__ bucket_off,
    int* __restrict__ gcursor, int nba)
{
    __shared__ int s[256];
    int t = threadIdx.x;
    int sum = 0;
    for (int b = 0; b < nba; b++) sum += partial[b * 256 + t];
    s[t] = sum;
    __syncthreads();
    for (int off = 1; off < 256; off <<= 1) {
        int v = (t >= off) ? s[t - off] : 0;
        __syncthreads();
        s[t] += v;
        __syncthreads();
    }
    int excl = s[t] - sum;
    bucket_off[t] = excl;
    gcursor[t] = excl;
    if (t == 255) bucket_off[256] = s[t];   // == E
}

// C: scatter (src,dst) pairs into bucket-contiguous ebuf. Each block reserves
// a contiguous chunk per bucket (one global atomic per (block,bucket)), then
// fills it via LDS cursors -> contiguous write runs, write-combining friendly.
__global__ __launch_bounds__(256) void bucket_scatter(
    const int* __restrict__ src, const int* __restrict__ dst,
    int* __restrict__ gcursor, int2* __restrict__ ebuf, int E, int tile)
{
    __shared__ int h[256];
    int t = threadIdx.x;
    h[t] = 0;
    __syncthreads();
    int estart = blockIdx.x * tile;
    int eend = min(E, estart + tile);
    for (int e = estart + t; e < eend; e += 256)
        atomicAdd(&h[dst[e] >> BSH], 1);
    __syncthreads();
    h[t] = atomicAdd(&gcursor[t], h[t]);   // h becomes block-local cursor base
    __syncthreads();
    for (int e = estart + t; e < eend; e += 256) {
        int d = dst[e];
        int p = atomicAdd(&h[d >> BSH], 1);
        ebuf[p] = make_int2(src[e], d);
    }
}

// D: one block per bucket — LDS count over 512 local nodes, LDS scan,
// emit row_start/dinv, then place csr_src within the bucket's 32KB region.
__global__ __launch_bounds__(256) void bucket_csr(
    const int2* __restrict__ ebuf, const int* __restrict__ bucket_off,
    int* __restrict__ row_start, int* __restrict__ csr_src,
    float* __restrict__ dinv, int n, int E)
{
    __shared__ int cnt[512];
    __shared__ int ps[256];
    int t = threadIdx.x;
    int blk = blockIdx.x;
    int node0 = blk << BSH;
    cnt[t] = 0; cnt[t + 256] = 0;
    __syncthreads();
    int bs = bucket_off[blk], be = bucket_off[blk + 1];
    for (int i = bs + t; i < be; i += 256)
        atomicAdd(&cnt[ebuf[i].y & 511], 1);
    __syncthreads();
    int c0 = cnt[2 * t], c1 = cnt[2 * t + 1];
    ps[t] = c0 + c1;
    __syncthreads();
    for (int off = 1; off < 256; off <<= 1) {
        int v = (t >= off) ? ps[t - off] : 0;
        __syncthreads();
        ps[t] += v;
        __syncthreads();
    }
    int pexcl = ps[t] - (c0 + c1);
    int e0 = pexcl, e1 = pexcl + c0;
    int g0 = node0 + 2 * t, g1 = g0 + 1;
    if (g0 < n) { row_start[g0] = bs + e0; dinv[g0] = rsqrtf((float)c0 + 1.0f); }
    if (g1 < n) { row_start[g1] = bs + e1; dinv[g1] = rsqrtf((float)c1 + 1.0f); }
    __syncthreads();
    cnt[2 * t] = e0; cnt[2 * t + 1] = e1;    // cnt becomes local cursor
    __syncthreads();
    for (int i = bs + t; i < be; i += 256) {
        int2 e = ebuf[i];
        int p = bs + atomicAdd(&cnt[e.y & 511], 1);
        csr_src[p] = e.x;
    }
    if (blk == gridDim.x - 1 && t == 0) row_start[n] = E;
}

// ---------------- per-layer kernels (R5) ----------------

// hprime(bf16) = dinv[row] * (xin @ W).  32 rows x 64 cols per block.
__global__ __launch_bounds__(256) void gemm_scale(
    const float* __restrict__ xin, const float* __restrict__ W,
    const float* __restrict__ dinv, __hip_bfloat16* __restrict__ hprime, int n)
{
    __shared__ float Ws[64 * 64];        // 16 KB
    __shared__ float Xs[32][65];         // 8.3 KB, +1 pad
    int t = threadIdx.x;
    for (int i = t; i < 64 * 64; i += 256) Ws[i] = W[i];
    int row0 = blockIdx.x * 32;
    for (int i = t; i < 32 * 64; i += 256) {
        int r = i >> 6, c = i & 63;
        int gr = row0 + r;
        Xs[r][c] = (gr < n) ? xin[(size_t)gr * DIMF + c] : 0.0f;
    }
    __syncthreads();
    int col = t & 63;
    int rbase = (t >> 6) * 8;            // 0,8,16,24
    float av[8];
#pragma unroll
    for (int rr = 0; rr < 8; rr++) av[rr] = 0.0f;
    for (int k = 0; k < 64; k++) {
        float w = Ws[k * 64 + col];
#pragma unroll
        for (int rr = 0; rr < 8; rr++)   // Xs read is wave-broadcast
            av[rr] = fmaf(Xs[rbase + rr][k], w, av[rr]);
    }
#pragma unroll
    for (int rr = 0; rr < 8; rr++) {
        int gr = row0 + rbase + rr;
        if (gr < n)
            hprime[(size_t)gr * DIMF + col] = __float2bfloat16(av[rr] * dinv[gr]);
    }
}

// 8 nodes per wave, 8 lanes per node (R5 best-known gather).
__global__ __launch_bounds__(256) void gather_relu(
    const unsigned int* __restrict__ hprime,  // bf16x2 packed, 32 uints/row
    const int* __restrict__ row_start, const int* __restrict__ csr_src,
    const float* __restrict__ dinv, const float* __restrict__ b,
    float* __restrict__ xout, int n)
{
    int wave = threadIdx.x >> 6;
    int lane = threadIdx.x & 63;
    int slot = lane >> 3;            // node slot 0..7
    int uoff = (lane & 7) << 2;      // uint index within 32-uint row
    int node = (blockIdx.x * 4 + wave) * 8 + slot;
    if (node >= n) return;

    int rs = row_start[node];
    int re = row_start[node + 1];
    int deg = re - rs;

    float acc[8];
#pragma unroll
    for (int i = 0; i < 8; i++) acc[i] = 0.0f;

#define ADDROW(v)                                                          \
    {                                                                      \
        acc[0] += __uint_as_float((v).x << 16);                            \
        acc[1] += __uint_as_float((v).x & 0xffff0000u);                    \
        acc[2] += __uint_as_float((v).y << 16);                            \
        acc[3] += __uint_as_float((v).y & 0xffff0000u);                    \
        acc[4] += __uint_as_float((v).z << 16);                            \
        acc[5] += __uint_as_float((v).z & 0xffff0000u);                    \
        acc[6] += __uint_as_float((v).w << 16);                            \
        acc[7] += __uint_as_float((v).w & 0xffff0000u);                    \
    }

    {   // self loop
        uint4 v = *(const uint4*)(hprime + (size_t)node * 32 + uoff);
        ADDROW(v);
    }
    if (deg > 0) {
        int idx = csr_src[rs];
        for (int k = 0; k < deg; k++) {
            int nxt = (k + 1 < deg) ? csr_src[rs + k + 1] : 0;  // prefetch
            uint4 v = *(const uint4*)(hprime + (size_t)idx * 32 + uoff);
            ADDROW(v);
            idx = nxt;
        }
    }
#undef ADDROW

    int f8 = uoff << 1;              // feature base = (lane&7)*8
    float dv = dinv[node];
    float4 o0, o1;
    o0.x = fmaxf(fmaf(dv, acc[0], b[f8 + 0]), 0.0f);
    o0.y = fmaxf(fmaf(dv, acc[1], b[f8 + 1]), 0.0f);
    o0.z = fmaxf(fmaf(dv, acc[2], b[f8 + 2]), 0.0f);
    o0.w = fmaxf(fmaf(dv, acc[3], b[f8 + 3]), 0.0f);
    o1.x = fmaxf(fmaf(dv, acc[4], b[f8 + 4]), 0.0f);
    o1.y = fmaxf(fmaf(dv, acc[5], b[f8 + 5]), 0.0f);
    o1.z = fmaxf(fmaf(dv, acc[6], b[f8 + 6]), 0.0f);
    o1.w = fmaxf(fmaf(dv, acc[7], b[f8 + 7]), 0.0f);
    float* op = xout + (size_t)node * DIMF + f8;
    *(float4*)(op)     = o0;
    *(float4*)(op + 4) = o1;
}

// MLP head + log_softmax. 128 threads = 128 nodes per block.
__global__ __launch_bounds__(128) void head_kernel(
    const float* __restrict__ x, const float* __restrict__ Wp1,
    const float* __restrict__ bp1, const float* __restrict__ Wp2,
    const float* __restrict__ bp2, float* __restrict__ out, int n)
{
    __shared__ float Xs[128][65];        // 33.3 KB
    __shared__ float W1s[64 * 32];       // 8 KB
    __shared__ float W2s[32 * 40];       // 5 KB
    __shared__ float b1s[32], b2s[40];
    int t = threadIdx.x;
    for (int i = t; i < 64 * 32; i += 128) W1s[i] = Wp1[i];
    for (int i = t; i < 32 * 40; i += 128) W2s[i] = Wp2[i];
    if (t < 32) b1s[t] = bp1[t];
    if (t < 40) b2s[t] = bp2[t];
    int row0 = blockIdx.x * 128;
    for (int i = t; i < 128 * 64; i += 128) {
        int r = i >> 6, c = i & 63;
        int gr = row0 + r;
        Xs[r][c] = (gr < n) ? x[(size_t)gr * DIMF + c] : 0.0f;
    }
    __syncthreads();
    int node = row0 + t;
    if (node >= n) return;

    float h[32];
#pragma unroll
    for (int j = 0; j < 32; j++) h[j] = b1s[j];
    for (int k = 0; k < 64; k++) {
        float xv = Xs[t][k];
#pragma unroll
        for (int j = 0; j < 32; j++) h[j] = fmaf(xv, W1s[k * 32 + j], h[j]);
    }
#pragma unroll
    for (int j = 0; j < 32; j++) h[j] = h[j] > 0.0f ? h[j] : 0.0f;

    float o[40];
#pragma unroll
    for (int j = 0; j < 40; j++) o[j] = b2s[j];
    for (int k = 0; k < 32; k++) {
        float hv = h[k];
#pragma unroll
        for (int j = 0; j < 40; j++) o[j] = fmaf(hv, W2s[k * 40 + j], o[j]);
    }
    float m = o[0];
#pragma unroll
    for (int j = 1; j < 40; j++) m = fmaxf(m, o[j]);
    float sum = 0.0f;
#pragma unroll
    for (int j = 0; j < 40; j++) sum += expf(o[j] - m);
    float lse = logf(sum) + m;
    float* op = out + (size_t)node * 40;
#pragma unroll
    for (int j = 0; j < 40; j++) op[j] = o[j] - lse;
}

extern "C" void kernel_launch(void* const* d_in, const int* in_sizes, int n_in,
                              void* d_out, int out_size, void* d_ws, size_t ws_size,
                              hipStream_t stream)
{
    const float* x  = (const float*)d_in[0];
    const int*   ei = (const int*)d_in[1];
    const int E = in_sizes[1] / 2;
    const int n = in_sizes[0] / DIMF;
    const int* src = ei;
    const int* dst = ei + E;
    const float* W[3] = {(const float*)d_in[3], (const float*)d_in[5], (const float*)d_in[7]};
    const float* b[3] = {(const float*)d_in[4], (const float*)d_in[6], (const float*)d_in[8]};
    const float* Wp1 = (const float*)d_in[9];
    const float* bp1 = (const float*)d_in[10];
    const float* Wp2 = (const float*)d_in[11];
    const float* bp2 = (const float*)d_in[12];
    float* out = (float*)d_out;

    const int NBK  = (n + 511) >> BSH;            // buckets (<= 256)
    const int tile = (E + NBA - 1) / NBA;

    // Workspace: partial[NBA*256] | bucket_off[257] | gcursor[256] |
    //            row_start[n+1] | dinv[n] | csr_src[E] | hp[n*64 bf16] |
    //            xbuf[n*64 f32]   (ebuf[E int2] aliases xbuf's first 8E bytes)
    char* p = (char*)d_ws;
    int* partial    = (int*)p;                p += (size_t)NBA * 256 * 4;
    int* bucket_off = (int*)p;                p += 257 * 4;
    int* gcursor    = (int*)p;                p += 256 * 4;
    p = (char*)(((size_t)p + 15) & ~(size_t)15);
    int* row_start  = (int*)p;                p += (size_t)(n + 1) * 4;
    float* dinv     = (float*)p;              p += (size_t)n * 4;
    p = (char*)(((size_t)p + 15) & ~(size_t)15);
    int* csr_src    = (int*)p;                p += (size_t)E * 4;
    p = (char*)(((size_t)p + 15) & ~(size_t)15);
    __hip_bfloat16* hp = (__hip_bfloat16*)p;  p += (size_t)n * DIMF * 2;
    p = (char*)(((size_t)p + 15) & ~(size_t)15);
    float* xbuf     = (float*)p;
    int2*  ebuf     = (int2*)xbuf;            // dead once layer-0 gather runs

    // --- CSR build (bucketed, LDS-heavy) ---
    hipLaunchKernelGGL(bucket_count,   dim3(NBA), dim3(256), 0, stream, dst, partial, E, tile);
    hipLaunchKernelGGL(bucket_scan,    dim3(1),   dim3(256), 0, stream, partial, bucket_off, gcursor, NBA);
    hipLaunchKernelGGL(bucket_scatter, dim3(NBA), dim3(256), 0, stream, src, dst, gcursor, ebuf, E, tile);
    hipLaunchKernelGGL(bucket_csr,     dim3(NBK), dim3(256), 0, stream, ebuf, bucket_off,
                       row_start, csr_src, dinv, n, E);

    // --- 3 GCN layers ---
    const float* xin = x;
    for (int l = 0; l < 3; l++) {
        hipLaunchKernelGGL(gemm_scale, dim3((n + 31) / 32), dim3(256), 0, stream,
                           xin, W[l], dinv, hp, n);
        hipLaunchKernelGGL(gather_relu, dim3((n + 31) / 32), dim3(256), 0, stream,
                           (const unsigned int*)hp, row_start, csr_src, dinv,
                           b[l], xbuf, n);
        xin = xbuf;
    }

    // --- head ---
    hipLaunchKernelGGL(head_kernel, dim3((n + 127) / 128), dim3(128), 0, stream,
                       xbuf, Wp1, bp1, Wp2, bp2, out, n);
}

// Round 9
// 469.706 us; speedup vs baseline: 1.7970x; 1.1476x over previous
//
#include <hip/hip_runtime.h>
#include <hip/hip_bf16.h>
#include <math.h>

// GCN stack: 3x [GCNConv + ReLU] + MLP head (64->32 relu ->40) + log_softmax.
// R9: (1) head_kernel rebuilt without the 33KB Xs LDS tile (R8 counters:
// 47KB LDS -> 9.8% occupancy, 9% VALUBusy, 83us for a ~15us roofline);
// W1/W2 stay in LDS (13KB), x rows loaded directly per-thread.
// (2) gather 2-deep unrolled with dual accumulators (MLP probe: two row
// loads in flight per lane-group).
// out[d] = relu(dinv[d] * (h'[d] + sum_{s in N_in(d)} h'[s]) + b),
// h' = dinv * (x @ W), h' stored bf16 flat [n][64].

#define DIMF 64
#define NBA  200     // blocks for bucket count/scatter
#define BSH  9       // 512 nodes per bucket

// ---------------- CSR build (bucketed) ----------------

__global__ __launch_bounds__(256) void bucket_count(
    const int* __restrict__ dst, int* __restrict__ partial, int E, int tile)
{
    __shared__ int h[256];
    int t = threadIdx.x;
    h[t] = 0;
    __syncthreads();
    int estart = blockIdx.x * tile;
    int eend = min(E, estart + tile);
    for (int e = estart + t; e < eend; e += 256)
        atomicAdd(&h[dst[e] >> BSH], 1);
    __syncthreads();
    partial[blockIdx.x * 256 + t] = h[t];
}

__global__ __launch_bounds__(256) void bucket_scan(
    const int* __restrict__ partial, int* __restrict__ bucket_off,
    int* __restrict__ gcursor, int nba)
{
    __shared__ int s[256];
    int t = threadIdx.x;
    int sum = 0;
    for (int b = 0; b < nba; b++) sum += partial[b * 256 + t];
    s[t] = sum;
    __syncthreads();
    for (int off = 1; off < 256; off <<= 1) {
        int v = (t >= off) ? s[t - off] : 0;
        __syncthreads();
        s[t] += v;
        __syncthreads();
    }
    int excl = s[t] - sum;
    bucket_off[t] = excl;
    gcursor[t] = excl;
    if (t == 255) bucket_off[256] = s[t];   // == E
}

__global__ __launch_bounds__(256) void bucket_scatter(
    const int* __restrict__ src, const int* __restrict__ dst,
    int* __restrict__ gcursor, int2* __restrict__ ebuf, int E, int tile)
{
    __shared__ int h[256];
    int t = threadIdx.x;
    h[t] = 0;
    __syncthreads();
    int estart = blockIdx.x * tile;
    int eend = min(E, estart + tile);
    for (int e = estart + t; e < eend; e += 256)
        atomicAdd(&h[dst[e] >> BSH], 1);
    __syncthreads();
    h[t] = atomicAdd(&gcursor[t], h[t]);   // h becomes block-local cursor base
    __syncthreads();
    for (int e = estart + t; e < eend; e += 256) {
        int d = dst[e];
        int p = atomicAdd(&h[d >> BSH], 1);
        ebuf[p] = make_int2(src[e], d);
    }
}

__global__ __launch_bounds__(256) void bucket_csr(
    const int2* __restrict__ ebuf, const int* __restrict__ bucket_off,
    int* __restrict__ row_start, int* __restrict__ csr_src,
    float* __restrict__ dinv, int n, int E)
{
    __shared__ int cnt[512];
    __shared__ int ps[256];
    int t = threadIdx.x;
    int blk = blockIdx.x;
    int node0 = blk << BSH;
    cnt[t] = 0; cnt[t + 256] = 0;
    __syncthreads();
    int bs = bucket_off[blk], be = bucket_off[blk + 1];
    for (int i = bs + t; i < be; i += 256)
        atomicAdd(&cnt[ebuf[i].y & 511], 1);
    __syncthreads();
    int c0 = cnt[2 * t], c1 = cnt[2 * t + 1];
    ps[t] = c0 + c1;
    __syncthreads();
    for (int off = 1; off < 256; off <<= 1) {
        int v = (t >= off) ? ps[t - off] : 0;
        __syncthreads();
        ps[t] += v;
        __syncthreads();
    }
    int pexcl = ps[t] - (c0 + c1);
    int e0 = pexcl, e1 = pexcl + c0;
    int g0 = node0 + 2 * t, g1 = g0 + 1;
    if (g0 < n) { row_start[g0] = bs + e0; dinv[g0] = rsqrtf((float)c0 + 1.0f); }
    if (g1 < n) { row_start[g1] = bs + e1; dinv[g1] = rsqrtf((float)c1 + 1.0f); }
    __syncthreads();
    cnt[2 * t] = e0; cnt[2 * t + 1] = e1;    // cnt becomes local cursor
    __syncthreads();
    for (int i = bs + t; i < be; i += 256) {
        int2 e = ebuf[i];
        int p = bs + atomicAdd(&cnt[e.y & 511], 1);
        csr_src[p] = e.x;
    }
    if (blk == gridDim.x - 1 && t == 0) row_start[n] = E;
}

// ---------------- per-layer kernels ----------------

// hprime(bf16) = dinv[row] * (xin @ W).  32 rows x 64 cols per block.
__global__ __launch_bounds__(256) void gemm_scale(
    const float* __restrict__ xin, const float* __restrict__ W,
    const float* __restrict__ dinv, __hip_bfloat16* __restrict__ hprime, int n)
{
    __shared__ float Ws[64 * 64];        // 16 KB
    __shared__ float Xs[32][65];         // 8.3 KB, +1 pad
    int t = threadIdx.x;
    for (int i = t; i < 64 * 64; i += 256) Ws[i] = W[i];
    int row0 = blockIdx.x * 32;
    for (int i = t; i < 32 * 64; i += 256) {
        int r = i >> 6, c = i & 63;
        int gr = row0 + r;
        Xs[r][c] = (gr < n) ? xin[(size_t)gr * DIMF + c] : 0.0f;
    }
    __syncthreads();
    int col = t & 63;
    int rbase = (t >> 6) * 8;            // 0,8,16,24
    float av[8];
#pragma unroll
    for (int rr = 0; rr < 8; rr++) av[rr] = 0.0f;
    for (int k = 0; k < 64; k++) {
        float w = Ws[k * 64 + col];
#pragma unroll
        for (int rr = 0; rr < 8; rr++)   // Xs read is wave-broadcast
            av[rr] = fmaf(Xs[rbase + rr][k], w, av[rr]);
    }
#pragma unroll
    for (int rr = 0; rr < 8; rr++) {
        int gr = row0 + rbase + rr;
        if (gr < n)
            hprime[(size_t)gr * DIMF + col] = __float2bfloat16(av[rr] * dinv[gr]);
    }
}

// 8 nodes per wave, 8 lanes per node; 2-deep unroll, dual accumulators.
__global__ __launch_bounds__(256) void gather_relu(
    const unsigned int* __restrict__ hprime,  // bf16x2 packed, 32 uints/row
    const int* __restrict__ row_start, const int* __restrict__ csr_src,
    const float* __restrict__ dinv, const float* __restrict__ b,
    float* __restrict__ xout, int n)
{
    int wave = threadIdx.x >> 6;
    int lane = threadIdx.x & 63;
    int slot = lane >> 3;            // node slot 0..7
    int uoff = (lane & 7) << 2;      // uint index within 32-uint row
    int node = (blockIdx.x * 4 + wave) * 8 + slot;
    if (node >= n) return;

    int rs = row_start[node];
    int re = row_start[node + 1];
    int deg = re - rs;

    float acc[8], accB[8];
#pragma unroll
    for (int i = 0; i < 8; i++) { acc[i] = 0.0f; accB[i] = 0.0f; }

#define ADDROW(a, v)                                                       \
    {                                                                      \
        a[0] += __uint_as_float((v).x << 16);                              \
        a[1] += __uint_as_float((v).x & 0xffff0000u);                      \
        a[2] += __uint_as_float((v).y << 16);                              \
        a[3] += __uint_as_float((v).y & 0xffff0000u);                      \
        a[4] += __uint_as_float((v).z << 16);                              \
        a[5] += __uint_as_float((v).z & 0xffff0000u);                      \
        a[6] += __uint_as_float((v).w << 16);                              \
        a[7] += __uint_as_float((v).w & 0xffff0000u);                      \
    }

    {   // self loop
        uint4 v = *(const uint4*)(hprime + (size_t)node * 32 + uoff);
        ADDROW(acc, v);
    }
    if (deg >= 2) {
        int i0 = csr_src[rs];
        int i1 = csr_src[rs + 1];
        int k = 0;
        for (; k + 2 <= deg; k += 2) {
            int n0 = (k + 2 < deg) ? csr_src[rs + k + 2] : 0;
            int n1 = (k + 3 < deg) ? csr_src[rs + k + 3] : 0;
            uint4 v0 = *(const uint4*)(hprime + (size_t)i0 * 32 + uoff);
            uint4 v1 = *(const uint4*)(hprime + (size_t)i1 * 32 + uoff);
            ADDROW(acc, v0);
            ADDROW(accB, v1);
            i0 = n0; i1 = n1;
        }
        if (k < deg) {   // odd tail: i0 already holds csr_src[rs+k]
            uint4 v0 = *(const uint4*)(hprime + (size_t)i0 * 32 + uoff);
            ADDROW(acc, v0);
        }
    } else if (deg == 1) {
        int i0 = csr_src[rs];
        uint4 v0 = *(const uint4*)(hprime + (size_t)i0 * 32 + uoff);
        ADDROW(acc, v0);
    }
#undef ADDROW

    int f8 = uoff << 1;              // feature base = (lane&7)*8
    float dv = dinv[node];
    float4 o0, o1;
    o0.x = fmaxf(fmaf(dv, acc[0] + accB[0], b[f8 + 0]), 0.0f);
    o0.y = fmaxf(fmaf(dv, acc[1] + accB[1], b[f8 + 1]), 0.0f);
    o0.z = fmaxf(fmaf(dv, acc[2] + accB[2], b[f8 + 2]), 0.0f);
    o0.w = fmaxf(fmaf(dv, acc[3] + accB[3], b[f8 + 3]), 0.0f);
    o1.x = fmaxf(fmaf(dv, acc[4] + accB[4], b[f8 + 4]), 0.0f);
    o1.y = fmaxf(fmaf(dv, acc[5] + accB[5], b[f8 + 5]), 0.0f);
    o1.z = fmaxf(fmaf(dv, acc[6] + accB[6], b[f8 + 6]), 0.0f);
    o1.w = fmaxf(fmaf(dv, acc[7] + accB[7], b[f8 + 7]), 0.0f);
    float* op = xout + (size_t)node * DIMF + f8;
    *(float4*)(op)     = o0;
    *(float4*)(op + 4) = o1;
}

// MLP head + log_softmax. 256 threads = 256 nodes per block.
// No Xs tile (R8: 47KB LDS -> 9.8% occupancy). W1/W2/b in LDS (13.3KB);
// each thread streams its own x row via float4 (lines fully consumed).
__global__ __launch_bounds__(256) void head_kernel(
    const float* __restrict__ x, const float* __restrict__ Wp1,
    const float* __restrict__ bp1, const float* __restrict__ Wp2,
    const float* __restrict__ bp2, float* __restrict__ out, int n)
{
    __shared__ float W1s[64 * 32];       // 8 KB
    __shared__ float W2s[32 * 40];       // 5 KB
    __shared__ float b1s[32], b2s[40];
    int t = threadIdx.x;
    for (int i = t; i < 64 * 32; i += 256) W1s[i] = Wp1[i];
    for (int i = t; i < 32 * 40; i += 256) W2s[i] = Wp2[i];
    if (t < 32) b1s[t] = bp1[t];
    if (t < 40) b2s[t] = bp2[t];
    __syncthreads();
    int node = blockIdx.x * 256 + t;
    if (node >= n) return;

    const float4* xp = (const float4*)(x + (size_t)node * DIMF);
    float h[32];
#pragma unroll
    for (int j = 0; j < 32; j++) h[j] = b1s[j];
#pragma unroll 4
    for (int k4 = 0; k4 < 16; k4++) {
        float4 xv = xp[k4];
        int k = k4 << 2;
#pragma unroll
        for (int j = 0; j < 32; j++) h[j] = fmaf(xv.x, W1s[(k + 0) * 32 + j], h[j]);
#pragma unroll
        for (int j = 0; j < 32; j++) h[j] = fmaf(xv.y, W1s[(k + 1) * 32 + j], h[j]);
#pragma unroll
        for (int j = 0; j < 32; j++) h[j] = fmaf(xv.z, W1s[(k + 2) * 32 + j], h[j]);
#pragma unroll
        for (int j = 0; j < 32; j++) h[j] = fmaf(xv.w, W1s[(k + 3) * 32 + j], h[j]);
    }
#pragma unroll
    for (int j = 0; j < 32; j++) h[j] = h[j] > 0.0f ? h[j] : 0.0f;

    float o[40];
#pragma unroll
    for (int j = 0; j < 40; j++) o[j] = b2s[j];
    for (int k = 0; k < 32; k++) {
        float hv = h[k];
#pragma unroll
        for (int j = 0; j < 40; j++) o[j] = fmaf(hv, W2s[k * 40 + j], o[j]);
    }
    float m = o[0];
#pragma unroll
    for (int j = 1; j < 40; j++) m = fmaxf(m, o[j]);
    float sum = 0.0f;
#pragma unroll
    for (int j = 0; j < 40; j++) sum += expf(o[j] - m);
    float lse = logf(sum) + m;
    float* op = out + (size_t)node * 40;
#pragma unroll
    for (int j = 0; j < 40; j++) op[j] = o[j] - lse;
}

extern "C" void kernel_launch(void* const* d_in, const int* in_sizes, int n_in,
                              void* d_out, int out_size, void* d_ws, size_t ws_size,
                              hipStream_t stream)
{
    const float* x  = (const float*)d_in[0];
    const int*   ei = (const int*)d_in[1];
    const int E = in_sizes[1] / 2;
    const int n = in_sizes[0] / DIMF;
    const int* src = ei;
    const int* dst = ei + E;
    const float* W[3] = {(const float*)d_in[3], (const float*)d_in[5], (const float*)d_in[7]};
    const float* b[3] = {(const float*)d_in[4], (const float*)d_in[6], (const float*)d_in[8]};
    const float* Wp1 = (const float*)d_in[9];
    const float* bp1 = (const float*)d_in[10];
    const float* Wp2 = (const float*)d_in[11];
    const float* bp2 = (const float*)d_in[12];
    float* out = (float*)d_out;

    const int NBK  = (n + 511) >> BSH;            // buckets (<= 256)
    const int tile = (E + NBA - 1) / NBA;

    // Workspace: partial[NBA*256] | bucket_off[257] | gcursor[256] |
    //            row_start[n+1] | dinv[n] | csr_src[E] | hp[n*64 bf16] |
    //            xbuf[n*64 f32]   (ebuf[E int2] aliases xbuf's first 8E bytes)
    char* p = (char*)d_ws;
    int* partial    = (int*)p;                p += (size_t)NBA * 256 * 4;
    int* bucket_off = (int*)p;                p += 257 * 4;
    int* gcursor    = (int*)p;                p += 256 * 4;
    p = (char*)(((size_t)p + 15) & ~(size_t)15);
    int* row_start  = (int*)p;                p += (size_t)(n + 1) * 4;
    float* dinv     = (float*)p;              p += (size_t)n * 4;
    p = (char*)(((size_t)p + 15) & ~(size_t)15);
    int* csr_src    = (int*)p;                p += (size_t)E * 4;
    p = (char*)(((size_t)p + 15) & ~(size_t)15);
    __hip_bfloat16* hp = (__hip_bfloat16*)p;  p += (size_t)n * DIMF * 2;
    p = (char*)(((size_t)p + 15) & ~(size_t)15);
    float* xbuf     = (float*)p;
    int2*  ebuf     = (int2*)xbuf;            // dead once layer-0 gather runs

    // --- CSR build (bucketed, LDS-heavy) ---
    hipLaunchKernelGGL(bucket_count,   dim3(NBA), dim3(256), 0, stream, dst, partial, E, tile);
    hipLaunchKernelGGL(bucket_scan,    dim3(1),   dim3(256), 0, stream, partial, bucket_off, gcursor, NBA);
    hipLaunchKernelGGL(bucket_scatter, dim3(NBA), dim3(256), 0, stream, src, dst, gcursor, ebuf, E, tile);
    hipLaunchKernelGGL(bucket_csr,     dim3(NBK), dim3(256), 0, stream, ebuf, bucket_off,
                       row_start, csr_src, dinv, n, E);

    // --- 3 GCN layers ---
    const float* xin = x;
    for (int l = 0; l < 3; l++) {
        hipLaunchKernelGGL(gemm_scale, dim3((n + 31) / 32), dim3(256), 0, stream,
                           xin, W[l], dinv, hp, n);
        hipLaunchKernelGGL(gather_relu, dim3((n + 31) / 32), dim3(256), 0, stream,
                           (const unsigned int*)hp, row_start, csr_src, dinv,
                           b[l], xbuf, n);
        xin = xbuf;
    }

    // --- head ---
    hipLaunchKernelGGL(head_kernel, dim3((n + 255) / 256), dim3(256), 0, stream,
                       xbuf, Wp1, bp1, Wp2, bp2, out, n);
}

// Round 10
// 462.289 us; speedup vs baseline: 1.8258x; 1.0160x over previous
//
#include <hip/hip_runtime.h>
#include <hip/hip_bf16.h>
#include <math.h>

// GCN stack: 3x [GCNConv + ReLU] + MLP head (64->32 relu ->40) + log_softmax.
// R10: (1) gather 4-deep unroll w/ 4 accumulator banks (R9: 2-deep was a
// 1.5-2x win -> gather is MLP-limited, push further). (2) inter-layer xbuf
// stored bf16 (halves gather writes + gemm/head reads). Layer-0 gemm reads
// f32 x; layers 1-2 read bf16.
// out[d] = relu(dinv[d] * (h'[d] + sum_{s in N_in(d)} h'[s]) + b),
// h' = dinv * (x @ W), h' stored bf16 flat [n][64].

#define DIMF 64
#define NBA  200     // blocks for bucket count/scatter
#define BSH  9       // 512 nodes per bucket

// ---------------- CSR build (bucketed) ----------------

__global__ __launch_bounds__(256) void bucket_count(
    const int* __restrict__ dst, int* __restrict__ partial, int E, int tile)
{
    __shared__ int h[256];
    int t = threadIdx.x;
    h[t] = 0;
    __syncthreads();
    int estart = blockIdx.x * tile;
    int eend = min(E, estart + tile);
    for (int e = estart + t; e < eend; e += 256)
        atomicAdd(&h[dst[e] >> BSH], 1);
    __syncthreads();
    partial[blockIdx.x * 256 + t] = h[t];
}

__global__ __launch_bounds__(256) void bucket_scan(
    const int* __restrict__ partial, int* __restrict__ bucket_off,
    int* __restrict__ gcursor, int nba)
{
    __shared__ int s[256];
    int t = threadIdx.x;
    int sum = 0;
    for (int b = 0; b < nba; b++) sum += partial[b * 256 + t];
    s[t] = sum;
    __syncthreads();
    for (int off = 1; off < 256; off <<= 1) {
        int v = (t >= off) ? s[t - off] : 0;
        __syncthreads();
        s[t] += v;
        __syncthreads();
    }
    int excl = s[t] - sum;
    bucket_off[t] = excl;
    gcursor[t] = excl;
    if (t == 255) bucket_off[256] = s[t];   // == E
}

__global__ __launch_bounds__(256) void bucket_scatter(
    const int* __restrict__ src, const int* __restrict__ dst,
    int* __restrict__ gcursor, int2* __restrict__ ebuf, int E, int tile)
{
    __shared__ int h[256];
    int t = threadIdx.x;
    h[t] = 0;
    __syncthreads();
    int estart = blockIdx.x * tile;
    int eend = min(E, estart + tile);
    for (int e = estart + t; e < eend; e += 256)
        atomicAdd(&h[dst[e] >> BSH], 1);
    __syncthreads();
    h[t] = atomicAdd(&gcursor[t], h[t]);   // h becomes block-local cursor base
    __syncthreads();
    for (int e = estart + t; e < eend; e += 256) {
        int d = dst[e];
        int p = atomicAdd(&h[d >> BSH], 1);
        ebuf[p] = make_int2(src[e], d);
    }
}

__global__ __launch_bounds__(256) void bucket_csr(
    const int2* __restrict__ ebuf, const int* __restrict__ bucket_off,
    int* __restrict__ row_start, int* __restrict__ csr_src,
    float* __restrict__ dinv, int n, int E)
{
    __shared__ int cnt[512];
    __shared__ int ps[256];
    int t = threadIdx.x;
    int blk = blockIdx.x;
    int node0 = blk << BSH;
    cnt[t] = 0; cnt[t + 256] = 0;
    __syncthreads();
    int bs = bucket_off[blk], be = bucket_off[blk + 1];
    for (int i = bs + t; i < be; i += 256)
        atomicAdd(&cnt[ebuf[i].y & 511], 1);
    __syncthreads();
    int c0 = cnt[2 * t], c1 = cnt[2 * t + 1];
    ps[t] = c0 + c1;
    __syncthreads();
    for (int off = 1; off < 256; off <<= 1) {
        int v = (t >= off) ? ps[t - off] : 0;
        __syncthreads();
        ps[t] += v;
        __syncthreads();
    }
    int pexcl = ps[t] - (c0 + c1);
    int e0 = pexcl, e1 = pexcl + c0;
    int g0 = node0 + 2 * t, g1 = g0 + 1;
    if (g0 < n) { row_start[g0] = bs + e0; dinv[g0] = rsqrtf((float)c0 + 1.0f); }
    if (g1 < n) { row_start[g1] = bs + e1; dinv[g1] = rsqrtf((float)c1 + 1.0f); }
    __syncthreads();
    cnt[2 * t] = e0; cnt[2 * t + 1] = e1;    // cnt becomes local cursor
    __syncthreads();
    for (int i = bs + t; i < be; i += 256) {
        int2 e = ebuf[i];
        int p = bs + atomicAdd(&cnt[e.y & 511], 1);
        csr_src[p] = e.x;
    }
    if (blk == gridDim.x - 1 && t == 0) row_start[n] = E;
}

// ---------------- per-layer kernels ----------------

// Layer 0: hprime(bf16) = dinv[row] * (x_f32 @ W). 32 rows x 64 cols / block.
__global__ __launch_bounds__(256) void gemm_scale_f32(
    const float* __restrict__ xin, const float* __restrict__ W,
    const float* __restrict__ dinv, __hip_bfloat16* __restrict__ hprime, int n)
{
    __shared__ float Ws[64 * 64];
    __shared__ float Xs[32][65];
    int t = threadIdx.x;
    for (int i = t; i < 64 * 64; i += 256) Ws[i] = W[i];
    int row0 = blockIdx.x * 32;
    for (int i = t; i < 32 * 64; i += 256) {
        int r = i >> 6, c = i & 63;
        int gr = row0 + r;
        Xs[r][c] = (gr < n) ? xin[(size_t)gr * DIMF + c] : 0.0f;
    }
    __syncthreads();
    int col = t & 63;
    int rbase = (t >> 6) * 8;
    float av[8];
#pragma unroll
    for (int rr = 0; rr < 8; rr++) av[rr] = 0.0f;
    for (int k = 0; k < 64; k++) {
        float w = Ws[k * 64 + col];
#pragma unroll
        for (int rr = 0; rr < 8; rr++)
            av[rr] = fmaf(Xs[rbase + rr][k], w, av[rr]);
    }
#pragma unroll
    for (int rr = 0; rr < 8; rr++) {
        int gr = row0 + rbase + rr;
        if (gr < n)
            hprime[(size_t)gr * DIMF + col] = __float2bfloat16(av[rr] * dinv[gr]);
    }
}

// Layers 1-2: same but xin is bf16 (uint4 = 8 feats staged to f32 LDS).
__global__ __launch_bounds__(256) void gemm_scale_bf16(
    const unsigned int* __restrict__ xin,   // bf16x2 packed, 32 uints/row
    const float* __restrict__ W,
    const float* __restrict__ dinv, __hip_bfloat16* __restrict__ hprime, int n)
{
    __shared__ float Ws[64 * 64];
    __shared__ float Xs[32][65];
    int t = threadIdx.x;
    for (int i = t; i < 64 * 64; i += 256) Ws[i] = W[i];
    int row0 = blockIdx.x * 32;
    {   // 256 threads x 8 feats = 2048 = 32x64
        int r = t >> 3, c = (t & 7) << 3;
        int gr = row0 + r;
        if (gr < n) {
            uint4 v = *(const uint4*)(xin + (size_t)gr * 32 + (c >> 1));
            Xs[r][c + 0] = __uint_as_float(v.x << 16);
            Xs[r][c + 1] = __uint_as_float(v.x & 0xffff0000u);
            Xs[r][c + 2] = __uint_as_float(v.y << 16);
            Xs[r][c + 3] = __uint_as_float(v.y & 0xffff0000u);
            Xs[r][c + 4] = __uint_as_float(v.z << 16);
            Xs[r][c + 5] = __uint_as_float(v.z & 0xffff0000u);
            Xs[r][c + 6] = __uint_as_float(v.w << 16);
            Xs[r][c + 7] = __uint_as_float(v.w & 0xffff0000u);
        } else {
#pragma unroll
            for (int j = 0; j < 8; j++) Xs[r][c + j] = 0.0f;
        }
    }
    __syncthreads();
    int col = t & 63;
    int rbase = (t >> 6) * 8;
    float av[8];
#pragma unroll
    for (int rr = 0; rr < 8; rr++) av[rr] = 0.0f;
    for (int k = 0; k < 64; k++) {
        float w = Ws[k * 64 + col];
#pragma unroll
        for (int rr = 0; rr < 8; rr++)
            av[rr] = fmaf(Xs[rbase + rr][k], w, av[rr]);
    }
#pragma unroll
    for (int rr = 0; rr < 8; rr++) {
        int gr = row0 + rbase + rr;
        if (gr < n)
            hprime[(size_t)gr * DIMF + col] = __float2bfloat16(av[rr] * dinv[gr]);
    }
}

// 8 nodes/wave, 8 lanes/node; 4-deep unroll, 4 accumulator banks; bf16 out.
__global__ __launch_bounds__(256) void gather_relu(
    const unsigned int* __restrict__ hprime,  // bf16x2 packed, 32 uints/row
    const int* __restrict__ row_start, const int* __restrict__ csr_src,
    const float* __restrict__ dinv, const float* __restrict__ b,
    __hip_bfloat16* __restrict__ xout, int n)
{
    int wave = threadIdx.x >> 6;
    int lane = threadIdx.x & 63;
    int slot = lane >> 3;            // node slot 0..7
    int uoff = (lane & 7) << 2;      // uint index within 32-uint row
    int node = (blockIdx.x * 4 + wave) * 8 + slot;
    if (node >= n) return;

    int rs = row_start[node];
    int re = row_start[node + 1];
    int deg = re - rs;

    float a0[8], a1[8], a2[8], a3[8];
#pragma unroll
    for (int i = 0; i < 8; i++) { a0[i] = 0.0f; a1[i] = 0.0f; a2[i] = 0.0f; a3[i] = 0.0f; }

#define ADDROW(a, v)                                                       \
    {                                                                      \
        a[0] += __uint_as_float((v).x << 16);                              \
        a[1] += __uint_as_float((v).x & 0xffff0000u);                      \
        a[2] += __uint_as_float((v).y << 16);                              \
        a[3] += __uint_as_float((v).y & 0xffff0000u);                      \
        a[4] += __uint_as_float((v).z << 16);                              \
        a[5] += __uint_as_float((v).z & 0xffff0000u);                      \
        a[6] += __uint_as_float((v).w << 16);                              \
        a[7] += __uint_as_float((v).w & 0xffff0000u);                      \
    }

    {   // self loop
        uint4 v = *(const uint4*)(hprime + (size_t)node * 32 + uoff);
        ADDROW(a0, v);
    }
    int k = 0;
    if (deg >= 4) {
        int i0 = csr_src[rs], i1 = csr_src[rs + 1];
        int i2 = csr_src[rs + 2], i3 = csr_src[rs + 3];
        for (; k + 4 <= deg; k += 4) {
            int m0 = (k + 4 < deg) ? csr_src[rs + k + 4] : 0;
            int m1 = (k + 5 < deg) ? csr_src[rs + k + 5] : 0;
            int m2 = (k + 6 < deg) ? csr_src[rs + k + 6] : 0;
            int m3 = (k + 7 < deg) ? csr_src[rs + k + 7] : 0;
            uint4 v0 = *(const uint4*)(hprime + (size_t)i0 * 32 + uoff);
            uint4 v1 = *(const uint4*)(hprime + (size_t)i1 * 32 + uoff);
            uint4 v2 = *(const uint4*)(hprime + (size_t)i2 * 32 + uoff);
            uint4 v3 = *(const uint4*)(hprime + (size_t)i3 * 32 + uoff);
            ADDROW(a0, v0);
            ADDROW(a1, v1);
            ADDROW(a2, v2);
            ADDROW(a3, v3);
            i0 = m0; i1 = m1; i2 = m2; i3 = m3;
        }
    }
    for (; k < deg; k++) {           // tail 0..3 edges
        int idx = csr_src[rs + k];
        uint4 v = *(const uint4*)(hprime + (size_t)idx * 32 + uoff);
        ADDROW(a0, v);
    }
#undef ADDROW

    int f8 = uoff << 1;              // feature base = (lane&7)*8
    float dv = dinv[node];
    unsigned int pk[4];
#pragma unroll
    for (int j = 0; j < 4; j++) {
        float lo = fmaxf(fmaf(dv, a0[2*j]   + a1[2*j]   + a2[2*j]   + a3[2*j],   b[f8 + 2*j]),     0.0f);
        float hi = fmaxf(fmaf(dv, a0[2*j+1] + a1[2*j+1] + a2[2*j+1] + a3[2*j+1], b[f8 + 2*j + 1]), 0.0f);
        unsigned int ul = (unsigned int)__bfloat16_as_ushort(__float2bfloat16(lo));
        unsigned int uh = (unsigned int)__bfloat16_as_ushort(__float2bfloat16(hi));
        pk[j] = ul | (uh << 16);
    }
    uint4 st = make_uint4(pk[0], pk[1], pk[2], pk[3]);
    *(uint4*)((unsigned short*)xout + (size_t)node * DIMF + f8) = st;
}

// MLP head + log_softmax; x rows are bf16. 256 nodes/block, 13KB LDS.
__global__ __launch_bounds__(256) void head_kernel(
    const unsigned int* __restrict__ x,     // bf16x2 packed, 32 uints/row
    const float* __restrict__ Wp1, const float* __restrict__ bp1,
    const float* __restrict__ Wp2, const float* __restrict__ bp2,
    float* __restrict__ out, int n)
{
    __shared__ float W1s[64 * 32];       // 8 KB
    __shared__ float W2s[32 * 40];       // 5 KB
    __shared__ float b1s[32], b2s[40];
    int t = threadIdx.x;
    for (int i = t; i < 64 * 32; i += 256) W1s[i] = Wp1[i];
    for (int i = t; i < 32 * 40; i += 256) W2s[i] = Wp2[i];
    if (t < 32) b1s[t] = bp1[t];
    if (t < 40) b2s[t] = bp2[t];
    __syncthreads();
    int node = blockIdx.x * 256 + t;
    if (node >= n) return;

    const uint4* xp = (const uint4*)(x + (size_t)node * 32);
    float h[32];
#pragma unroll
    for (int j = 0; j < 32; j++) h[j] = b1s[j];
#pragma unroll
    for (int k8 = 0; k8 < 8; k8++) {
        uint4 v = xp[k8];
        float xv[8];
        xv[0] = __uint_as_float(v.x << 16);
        xv[1] = __uint_as_float(v.x & 0xffff0000u);
        xv[2] = __uint_as_float(v.y << 16);
        xv[3] = __uint_as_float(v.y & 0xffff0000u);
        xv[4] = __uint_as_float(v.z << 16);
        xv[5] = __uint_as_float(v.z & 0xffff0000u);
        xv[6] = __uint_as_float(v.w << 16);
        xv[7] = __uint_as_float(v.w & 0xffff0000u);
        int k = k8 << 3;
#pragma unroll
        for (int kk = 0; kk < 8; kk++)
#pragma unroll
            for (int j = 0; j < 32; j++)
                h[j] = fmaf(xv[kk], W1s[(k + kk) * 32 + j], h[j]);
    }
#pragma unroll
    for (int j = 0; j < 32; j++) h[j] = h[j] > 0.0f ? h[j] : 0.0f;

    float o[40];
#pragma unroll
    for (int j = 0; j < 40; j++) o[j] = b2s[j];
    for (int k = 0; k < 32; k++) {
        float hv = h[k];
#pragma unroll
        for (int j = 0; j < 40; j++) o[j] = fmaf(hv, W2s[k * 40 + j], o[j]);
    }
    float m = o[0];
#pragma unroll
    for (int j = 1; j < 40; j++) m = fmaxf(m, o[j]);
    float sum = 0.0f;
#pragma unroll
    for (int j = 0; j < 40; j++) sum += expf(o[j] - m);
    float lse = logf(sum) + m;
    float* op = out + (size_t)node * 40;
#pragma unroll
    for (int j = 0; j < 40; j++) op[j] = o[j] - lse;
}

extern "C" void kernel_launch(void* const* d_in, const int* in_sizes, int n_in,
                              void* d_out, int out_size, void* d_ws, size_t ws_size,
                              hipStream_t stream)
{
    const float* x  = (const float*)d_in[0];
    const int*   ei = (const int*)d_in[1];
    const int E = in_sizes[1] / 2;
    const int n = in_sizes[0] / DIMF;
    const int* src = ei;
    const int* dst = ei + E;
    const float* W[3] = {(const float*)d_in[3], (const float*)d_in[5], (const float*)d_in[7]};
    const float* b[3] = {(const float*)d_in[4], (const float*)d_in[6], (const float*)d_in[8]};
    const float* Wp1 = (const float*)d_in[9];
    const float* bp1 = (const float*)d_in[10];
    const float* Wp2 = (const float*)d_in[11];
    const float* bp2 = (const float*)d_in[12];
    float* out = (float*)d_out;

    const int NBK  = (n + 511) >> BSH;            // buckets (<= 256)
    const int tile = (E + NBA - 1) / NBA;

    // Workspace: partial[NBA*256] | bucket_off[257] | gcursor[256] |
    //            row_start[n+1] | dinv[n] | csr_src[E] | hp[n*64 bf16] |
    //            xbuf[n*64 bf16]  (ebuf[E int2] aliases xbuf)
    char* p = (char*)d_ws;
    int* partial    = (int*)p;                p += (size_t)NBA * 256 * 4;
    int* bucket_off = (int*)p;                p += 257 * 4;
    int* gcursor    = (int*)p;                p += 256 * 4;
    p = (char*)(((size_t)p + 15) & ~(size_t)15);
    int* row_start  = (int*)p;                p += (size_t)(n + 1) * 4;
    float* dinv     = (float*)p;              p += (size_t)n * 4;
    p = (char*)(((size_t)p + 15) & ~(size_t)15);
    int* csr_src    = (int*)p;                p += (size_t)E * 4;
    p = (char*)(((size_t)p + 15) & ~(size_t)15);
    __hip_bfloat16* hp = (__hip_bfloat16*)p;  p += (size_t)n * DIMF * 2;
    p = (char*)(((size_t)p + 15) & ~(size_t)15);
    __hip_bfloat16* xbuf = (__hip_bfloat16*)p;  p += (size_t)n * DIMF * 2;
    // ebuf needs E*8 bytes; alias xbuf + following scratch (dead until gather)
    int2* ebuf      = (int2*)xbuf;

    // --- CSR build (bucketed, LDS-heavy) ---
    hipLaunchKernelGGL(bucket_count,   dim3(NBA), dim3(256), 0, stream, dst, partial, E, tile);
    hipLaunchKernelGGL(bucket_scan,    dim3(1),   dim3(256), 0, stream, partial, bucket_off, gcursor, NBA);
    hipLaunchKernelGGL(bucket_scatter, dim3(NBA), dim3(256), 0, stream, src, dst, gcursor, ebuf, E, tile);
    hipLaunchKernelGGL(bucket_csr,     dim3(NBK), dim3(256), 0, stream, ebuf, bucket_off,
                       row_start, csr_src, dinv, n, E);

    // --- 3 GCN layers ---
    hipLaunchKernelGGL(gemm_scale_f32, dim3((n + 31) / 32), dim3(256), 0, stream,
                       x, W[0], dinv, hp, n);
    hipLaunchKernelGGL(gather_relu, dim3((n + 31) / 32), dim3(256), 0, stream,
                       (const unsigned int*)hp, row_start, csr_src, dinv,
                       b[0], xbuf, n);
    for (int l = 1; l < 3; l++) {
        hipLaunchKernelGGL(gemm_scale_bf16, dim3((n + 31) / 32), dim3(256), 0, stream,
                           (const unsigned int*)xbuf, W[l], dinv, hp, n);
        hipLaunchKernelGGL(gather_relu, dim3((n + 31) / 32), dim3(256), 0, stream,
                           (const unsigned int*)hp, row_start, csr_src, dinv,
                           b[l], xbuf, n);
    }

    // --- head ---
    hipLaunchKernelGGL(head_kernel, dim3((n + 255) / 256), dim3(256), 0, stream,
                       (const unsigned int*)xbuf, Wp1, bp1, Wp2, bp2, out, n);
}